// Round 1
// baseline (1058.112 us; speedup 1.0000x reference)
//
#include <hip/hip_runtime.h>
#include <hip/hip_bf16.h>
#include <stdint.h>

using bf16x8 = __attribute__((ext_vector_type(8))) short;
using f32x4  = __attribute__((ext_vector_type(4))) float;

#define HP 58
#define WP 58

// ---------------------------------------------------------------------------
// Zero the padded intermediate (borders must be 0; ws is poisoned 0xAA).
// ---------------------------------------------------------------------------
__global__ __launch_bounds__(256) void zero_ws(uint4* __restrict__ p, long n16) {
  long stride = (long)gridDim.x * blockDim.x;
  uint4 z; z.x = z.y = z.z = z.w = 0u;
  for (long i = (long)blockIdx.x * blockDim.x + threadIdx.x; i < n16; i += stride) p[i] = z;
}

// ---------------------------------------------------------------------------
// Weight prep: W[co][ci][kh][kw] f32  ->  Wb[kpos][co][ci] bf16
// ---------------------------------------------------------------------------
__global__ __launch_bounds__(256) void wprep(const float* __restrict__ w,
                                             unsigned short* __restrict__ out, int Cg) {
  int n = 9 * Cg * Cg;
  int stride = gridDim.x * blockDim.x;
  for (int i = blockIdx.x * blockDim.x + threadIdx.x; i < n; i += stride) {
    int kpos = i / (Cg * Cg);
    int r = i - kpos * Cg * Cg;
    int co = r / Cg;
    int ci = r - co * Cg;
    __hip_bfloat16 v = __float2bfloat16(w[(co * Cg + ci) * 9 + kpos]);
    out[(kpos * Cg + co) * Cg + ci] = *reinterpret_cast<unsigned short*>(&v);
  }
}

// ---------------------------------------------------------------------------
// Temporal depthwise conv (generic, reads the weight arrays) + layout change:
// x[nt][c][h][w] f32 (NCHW)  ->  y_pad[b][h+1][w+1][c] bf16 (channels-last,
// 58x58 spatially padded frame). One block per (b, h); LDS transpose so both
// global read (w-contiguous) and global write (c-contiguous) are coalesced.
// ---------------------------------------------------------------------------
__global__ __launch_bounds__(256) void temporal_stage(
    const float* __restrict__ x,
    const float* __restrict__ w11, const float* __restrict__ w13,
    const float* __restrict__ w15, const float* __restrict__ w17,
    const float* __restrict__ w21, const float* __restrict__ w23,
    const float* __restrict__ w25, const float* __restrict__ w27,
    unsigned short* __restrict__ ypad)
{
  __shared__ float Ls[128][57];   // +1 pad -> conflict-free transpose
  int bid = blockIdx.x;
  int b = bid / 56;
  int h = bid - b * 56;
  int t = b & 7;                  // position within the 8-frame segment
  int tid = threadIdx.x;

  for (int half = 0; half < 2; ++half) {
    int cbase = half * 128;
    // phase 1: read x (coalesced over w), apply temporal conv, stash in LDS
    for (int idx = tid; idx < 128 * 56; idx += 256) {
      int cl = idx / 56;
      int w_ = idx - cl * 56;
      int c = cbase + cl;
      const float* wg; int K, cloc;
      if (c < 64) {
        int g = c >> 4; cloc = c & 15; K = 2 * g + 1;
        wg = (g == 0) ? w11 : (g == 1) ? w13 : (g == 2) ? w15 : w17;
      } else {
        int g = (c - 64) / 48; cloc = (c - 64) - g * 48; K = 2 * g + 1;
        wg = (g == 0) ? w21 : (g == 1) ? w23 : (g == 2) ? w25 : w27;
      }
      int P = (K - 1) >> 1;
      float acc = 0.f;
      for (int k = 0; k < K; ++k) {
        float wv = wg[cloc * K + k];
        int tt = t + k - P;                 // target frame within segment
        if (wv != 0.f && tt >= 0 && tt < 8) {
          acc += wv * x[(((long)(b + k - P) * 256 + c) * 56 + h) * 56 + w_];
        }
      }
      Ls[cl][w_] = acc;
    }
    __syncthreads();
    // phase 2: write channels-last (coalesced over c)
    for (int idx = tid; idx < 56 * 128; idx += 256) {
      int w_ = idx >> 7;
      int cl = idx & 127;
      __hip_bfloat16 v = __float2bfloat16(Ls[cl][w_]);
      ypad[(((long)b * HP + (h + 1)) * WP + (w_ + 1)) * 256 + cbase + cl] =
          *reinterpret_cast<unsigned short*>(&v);
    }
    __syncthreads();
  }
}

// ---------------------------------------------------------------------------
// Implicit-GEMM 3x3 conv, bf16 MFMA.
//   out[b][co][p] = sum_{kpos, ci} ypad[b][ph+kh][pw+kw][ci_base+ci] * Wb[kpos][co][ci]
// Tile: M=64 pixels x N=64 co, BK=64. 4 waves, each a 32x32 quadrant
// (2x2 of 16x16x32 MFMA tiles). LDS rows padded 64->72 (uniform banks).
// A-frag: A[m=lane&15][k=quad*8+j]; B-frag: B[k=quad*8+j][n=lane&15];
// C/D: row=quad*4+reg, col=lane&15 (measured layouts, m89/m91).
// ---------------------------------------------------------------------------
__global__ __launch_bounds__(256) void conv_gemm(
    const unsigned short* __restrict__ ypad,  // [64][58][58][256] bf16
    const unsigned short* __restrict__ wb,    // [9][Cg][Cg] bf16
    float* __restrict__ out,                  // [64][256][56][56] f32
    int Cg, int co_base, int ci_base)
{
  __shared__ __align__(16) unsigned short As[64][72];
  __shared__ __align__(16) unsigned short Bs[64][72];

  int tid = threadIdx.x;
  int b  = blockIdx.x / 49;
  int p0 = (blockIdx.x - b * 49) * 64;   // 3136 = 49*64 pixels per frame
  int ny = blockIdx.y;

  // staging constants: 4 threads per row, 16 elems (2x uint4) each
  int sm   = tid >> 2;          // 0..63 tile row
  int koff = (tid & 3) * 16;    // 0,16,32,48
  int p  = p0 + sm;
  int ph = p / 56;
  int pw = p - ph * 56;
  const unsigned short* arow = ypad + (((long)b * HP + ph) * WP + pw) * 256 + ci_base;
  const unsigned short* brow = wb + (long)(ny * 64 + sm) * Cg;

  f32x4 acc[2][2];
  #pragma unroll
  for (int i = 0; i < 2; ++i)
    #pragma unroll
    for (int j = 0; j < 2; ++j) acc[i][j] = (f32x4){0.f, 0.f, 0.f, 0.f};

  int wv   = tid >> 6;
  int lane = tid & 63;
  int mi   = (wv >> 1) * 32;
  int ni   = (wv & 1) * 32;
  int l15  = lane & 15;
  int quad = lane >> 4;
  int qk   = quad * 8;

  int nkc = Cg >> 6;  // K-chunks of 64
  for (int kpos = 0; kpos < 9; ++kpos) {
    int kh = kpos / 3;
    int kw = kpos - kh * 3;
    const unsigned short* asrc0 = arow + (kh * WP + kw) * 256;
    const unsigned short* bsrc0 = brow + kpos * Cg * Cg;
    for (int kc = 0; kc < nkc; ++kc) {
      const unsigned short* asrc = asrc0 + kc * 64 + koff;
      const unsigned short* bsrc = bsrc0 + kc * 64 + koff;
      *reinterpret_cast<uint4*>(&As[sm][koff])     = *reinterpret_cast<const uint4*>(asrc);
      *reinterpret_cast<uint4*>(&As[sm][koff + 8]) = *reinterpret_cast<const uint4*>(asrc + 8);
      *reinterpret_cast<uint4*>(&Bs[sm][koff])     = *reinterpret_cast<const uint4*>(bsrc);
      *reinterpret_cast<uint4*>(&Bs[sm][koff + 8]) = *reinterpret_cast<const uint4*>(bsrc + 8);
      __syncthreads();
      #pragma unroll
      for (int kk = 0; kk < 2; ++kk) {
        int ko = kk * 32 + qk;
        bf16x8 a0 = *reinterpret_cast<const bf16x8*>(&As[mi + l15][ko]);
        bf16x8 a1 = *reinterpret_cast<const bf16x8*>(&As[mi + 16 + l15][ko]);
        bf16x8 b0 = *reinterpret_cast<const bf16x8*>(&Bs[ni + l15][ko]);
        bf16x8 b1 = *reinterpret_cast<const bf16x8*>(&Bs[ni + 16 + l15][ko]);
        acc[0][0] = __builtin_amdgcn_mfma_f32_16x16x32_bf16(a0, b0, acc[0][0], 0, 0, 0);
        acc[0][1] = __builtin_amdgcn_mfma_f32_16x16x32_bf16(a0, b1, acc[0][1], 0, 0, 0);
        acc[1][0] = __builtin_amdgcn_mfma_f32_16x16x32_bf16(a1, b0, acc[1][0], 0, 0, 0);
        acc[1][1] = __builtin_amdgcn_mfma_f32_16x16x32_bf16(a1, b1, acc[1][1], 0, 0, 0);
      }
      __syncthreads();
    }
  }

  // epilogue: row = quad*4 + reg, col = lane&15; 16 consecutive p per co
  // across the wave-tile -> L2 merges into full lines.
  #pragma unroll
  for (int i = 0; i < 2; ++i) {
    int rowb = mi + i * 16 + quad * 4;
    #pragma unroll
    for (int j = 0; j < 2; ++j) {
      int col = ni + j * 16 + l15;
      int co = co_base + ny * 64 + col;
      float* obase = out + ((long)b * 256 + co) * 3136 + p0 + rowb;
      #pragma unroll
      for (int r = 0; r < 4; ++r) obase[r] = acc[i][j][r];
    }
  }
}

// ---------------------------------------------------------------------------
extern "C" void kernel_launch(void* const* d_in, const int* in_sizes, int n_in,
                              void* d_out, int out_size, void* d_ws, size_t ws_size,
                              hipStream_t stream) {
  const float* x    = (const float*)d_in[0];
  const float* w11  = (const float*)d_in[1];
  const float* w13  = (const float*)d_in[2];
  const float* w15  = (const float*)d_in[3];
  const float* w17  = (const float*)d_in[4];
  const float* w21  = (const float*)d_in[5];
  const float* w23  = (const float*)d_in[6];
  const float* w25  = (const float*)d_in[7];
  const float* w27  = (const float*)d_in[8];
  const float* w2d1 = (const float*)d_in[9];
  const float* w2d2 = (const float*)d_in[10];
  float* out = (float*)d_out;

  unsigned short* ypad = (unsigned short*)d_ws;
  size_t ypad_elems = (size_t)64 * HP * WP * 256;       // 55.1M bf16 = 110 MB
  unsigned short* wb1 = ypad + ypad_elems;              // 9*64*64
  unsigned short* wb2 = wb1 + 9 * 64 * 64;              // 9*192*192

  long n16 = (long)(ypad_elems * 2 / 16);
  hipLaunchKernelGGL(zero_ws, dim3(2048), dim3(256), 0, stream, (uint4*)ypad, n16);
  hipLaunchKernelGGL(wprep, dim3(32),  dim3(256), 0, stream, w2d1, wb1, 64);
  hipLaunchKernelGGL(wprep, dim3(256), dim3(256), 0, stream, w2d2, wb2, 192);
  hipLaunchKernelGGL(temporal_stage, dim3(64 * 56), dim3(256), 0, stream,
                     x, w11, w13, w15, w17, w21, w23, w25, w27, ypad);
  // group 1: 64 -> 64 channels
  hipLaunchKernelGGL(conv_gemm, dim3(3136, 1), dim3(256), 0, stream, ypad, wb1, out, 64, 0, 0);
  // group 2: 192 -> 192 channels
  hipLaunchKernelGGL(conv_gemm, dim3(3136, 3), dim3(256), 0, stream, ypad, wb2, out, 192, 64, 64);
}

// Round 2
// 849.209 us; speedup vs baseline: 1.2460x; 1.2460x over previous
//
#include <hip/hip_runtime.h>
#include <hip/hip_bf16.h>
#include <stdint.h>

using bf16x8 = __attribute__((ext_vector_type(8))) short;
using f32x4  = __attribute__((ext_vector_type(4))) float;

#define HP 58
#define WP 58

// ---------------------------------------------------------------------------
// Zero only the pad ring of ypad (228 border pixels per 58x58 frame, 256 ch).
// Interior is fully overwritten by temporal_stage. 466944 uint4 items total.
// ---------------------------------------------------------------------------
__global__ __launch_bounds__(256) void zero_ring(uint4* __restrict__ ypad) {
  uint4 z; z.x = z.y = z.z = z.w = 0u;
  int i = blockIdx.x * blockDim.x + threadIdx.x;   // grid sized exactly
  int v = i & 31;                                  // uint4 within pixel (32*16B=512B=256 bf16)
  int pr = i >> 5;
  int b = pr / 228;
  int r = pr - b * 228;
  int h, w;
  if (r < 58)       { h = 0;  w = r; }
  else if (r < 116) { h = 57; w = r - 58; }
  else { int rr = r - 116; h = 1 + (rr >> 1); w = (rr & 1) * 57; }
  ypad[(((long)b * HP + h) * WP + w) * 32 + v] = z;
}

// ---------------------------------------------------------------------------
// Per-channel dense tap table: wtab[c][j], j=0..6 <-> dt=j-3 (j=7 unused pad).
// ---------------------------------------------------------------------------
__global__ void wtab_prep(const float* __restrict__ w11, const float* __restrict__ w13,
                          const float* __restrict__ w15, const float* __restrict__ w17,
                          const float* __restrict__ w21, const float* __restrict__ w23,
                          const float* __restrict__ w25, const float* __restrict__ w27,
                          float* __restrict__ wtab) {
  int c = threadIdx.x;   // one block of 256
  float tv[8];
  #pragma unroll
  for (int j = 0; j < 8; ++j) tv[j] = 0.f;
  const float* wg; int K, cloc;
  if (c < 64) {
    int g = c >> 4; cloc = c & 15; K = 2 * g + 1;
    wg = (g == 0) ? w11 : (g == 1) ? w13 : (g == 2) ? w15 : w17;
  } else {
    int g = (c - 64) / 48; cloc = (c - 64) - g * 48; K = 2 * g + 1;
    wg = (g == 0) ? w21 : (g == 1) ? w23 : (g == 2) ? w25 : w27;
  }
  int P = (K - 1) >> 1;
  for (int k = 0; k < K; ++k) tv[3 + k - P] = wg[cloc * K + k];
  #pragma unroll
  for (int j = 0; j < 8; ++j) wtab[c * 8 + j] = tv[j];
}

// ---------------------------------------------------------------------------
// Weight prep: W[co][ci][kh][kw] f32  ->  Wb[kpos][co][ci] bf16
// ---------------------------------------------------------------------------
__global__ __launch_bounds__(256) void wprep(const float* __restrict__ w,
                                             unsigned short* __restrict__ out, int Cg) {
  int n = 9 * Cg * Cg;
  int stride = gridDim.x * blockDim.x;
  for (int i = blockIdx.x * blockDim.x + threadIdx.x; i < n; i += stride) {
    int kpos = i / (Cg * Cg);
    int r = i - kpos * Cg * Cg;
    int co = r / Cg;
    int ci = r - co * Cg;
    __hip_bfloat16 v = __float2bfloat16(w[(co * Cg + ci) * 9 + kpos]);
    out[(kpos * Cg + co) * Cg + ci] = *reinterpret_cast<unsigned short*>(&v);
  }
}

// ---------------------------------------------------------------------------
// Temporal depthwise conv + NCHW->padded-NHWC(bf16) layout change.
// Branchless dense 7-tap: all 7 frame loads issued unconditionally (frame
// index clamped into the segment; weight zeroed by a block-uniform select),
// so each item has ~14 independent loads in flight -> latency-bound fix.
// ---------------------------------------------------------------------------
__global__ __launch_bounds__(256) void temporal_stage(
    const float* __restrict__ x, const float* __restrict__ wtab,
    unsigned short* __restrict__ ypad)
{
  __shared__ float Ls[128][57];   // +1 pad -> conflict-free transpose
  int bid = blockIdx.x;
  int b = bid / 56;
  int h = bid - b * 56;
  int t = b & 7;                  // position within the 8-frame segment
  int tid = threadIdx.x;

  for (int half = 0; half < 2; ++half) {
    int cbase = half * 128;
    // phase 1: coalesced-over-w reads, dense temporal taps, stash f32 in LDS
    for (int idx = tid; idx < 128 * 56; idx += 256) {
      int cl = idx / 56;
      int w_ = idx - cl * 56;
      int c = cbase + cl;
      const float* wt = wtab + c * 8;
      const float* xp = x + ((long)b * 256 + c) * 3136 + h * 56 + w_;
      float acc = 0.f;
      #pragma unroll
      for (int j = 0; j < 7; ++j) {
        int tt = t + j - 3;                               // block-uniform
        int dtc = (tt < 0 ? 0 : (tt > 7 ? 7 : tt)) - t;   // clamped dt (uniform)
        float wj = wt[j];
        if (tt < 0 || tt > 7) wj = 0.f;                   // uniform select
        acc += wj * xp[(long)dtc * 802816];               // 256*3136 elems/frame
      }
      Ls[cl][w_] = acc;
    }
    __syncthreads();
    // phase 2: write channels-last (coalesced over c)
    for (int idx = tid; idx < 56 * 128; idx += 256) {
      int w_ = idx >> 7;
      int cl = idx & 127;
      __hip_bfloat16 v = __float2bfloat16(Ls[cl][w_]);
      ypad[(((long)b * HP + (h + 1)) * WP + (w_ + 1)) * 256 + cbase + cl] =
          *reinterpret_cast<unsigned short*>(&v);
    }
    __syncthreads();
  }
}

// ---------------------------------------------------------------------------
// Implicit-GEMM 3x3 conv, bf16 MFMA (unchanged this round).
// ---------------------------------------------------------------------------
__global__ __launch_bounds__(256) void conv_gemm(
    const unsigned short* __restrict__ ypad,  // [64][58][58][256] bf16
    const unsigned short* __restrict__ wb,    // [9][Cg][Cg] bf16
    float* __restrict__ out,                  // [64][256][56][56] f32
    int Cg, int co_base, int ci_base)
{
  __shared__ __align__(16) unsigned short As[64][72];
  __shared__ __align__(16) unsigned short Bs[64][72];

  int tid = threadIdx.x;
  int b  = blockIdx.x / 49;
  int p0 = (blockIdx.x - b * 49) * 64;
  int ny = blockIdx.y;

  int sm   = tid >> 2;
  int koff = (tid & 3) * 16;
  int p  = p0 + sm;
  int ph = p / 56;
  int pw = p - ph * 56;
  const unsigned short* arow = ypad + (((long)b * HP + ph) * WP + pw) * 256 + ci_base;
  const unsigned short* brow = wb + (long)(ny * 64 + sm) * Cg;

  f32x4 acc[2][2];
  #pragma unroll
  for (int i = 0; i < 2; ++i)
    #pragma unroll
    for (int j = 0; j < 2; ++j) acc[i][j] = (f32x4){0.f, 0.f, 0.f, 0.f};

  int wv   = tid >> 6;
  int lane = tid & 63;
  int mi   = (wv >> 1) * 32;
  int ni   = (wv & 1) * 32;
  int l15  = lane & 15;
  int quad = lane >> 4;
  int qk   = quad * 8;

  int nkc = Cg >> 6;
  for (int kpos = 0; kpos < 9; ++kpos) {
    int kh = kpos / 3;
    int kw = kpos - kh * 3;
    const unsigned short* asrc0 = arow + (kh * WP + kw) * 256;
    const unsigned short* bsrc0 = brow + kpos * Cg * Cg;
    for (int kc = 0; kc < nkc; ++kc) {
      const unsigned short* asrc = asrc0 + kc * 64 + koff;
      const unsigned short* bsrc = bsrc0 + kc * 64 + koff;
      *reinterpret_cast<uint4*>(&As[sm][koff])     = *reinterpret_cast<const uint4*>(asrc);
      *reinterpret_cast<uint4*>(&As[sm][koff + 8]) = *reinterpret_cast<const uint4*>(asrc + 8);
      *reinterpret_cast<uint4*>(&Bs[sm][koff])     = *reinterpret_cast<const uint4*>(bsrc);
      *reinterpret_cast<uint4*>(&Bs[sm][koff + 8]) = *reinterpret_cast<const uint4*>(bsrc + 8);
      __syncthreads();
      #pragma unroll
      for (int kk = 0; kk < 2; ++kk) {
        int ko = kk * 32 + qk;
        bf16x8 a0 = *reinterpret_cast<const bf16x8*>(&As[mi + l15][ko]);
        bf16x8 a1 = *reinterpret_cast<const bf16x8*>(&As[mi + 16 + l15][ko]);
        bf16x8 b0 = *reinterpret_cast<const bf16x8*>(&Bs[ni + l15][ko]);
        bf16x8 b1 = *reinterpret_cast<const bf16x8*>(&Bs[ni + 16 + l15][ko]);
        acc[0][0] = __builtin_amdgcn_mfma_f32_16x16x32_bf16(a0, b0, acc[0][0], 0, 0, 0);
        acc[0][1] = __builtin_amdgcn_mfma_f32_16x16x32_bf16(a0, b1, acc[0][1], 0, 0, 0);
        acc[1][0] = __builtin_amdgcn_mfma_f32_16x16x32_bf16(a1, b0, acc[1][0], 0, 0, 0);
        acc[1][1] = __builtin_amdgcn_mfma_f32_16x16x32_bf16(a1, b1, acc[1][1], 0, 0, 0);
      }
      __syncthreads();
    }
  }

  #pragma unroll
  for (int i = 0; i < 2; ++i) {
    int rowb = mi + i * 16 + quad * 4;
    #pragma unroll
    for (int j = 0; j < 2; ++j) {
      int col = ni + j * 16 + l15;
      int co = co_base + ny * 64 + col;
      float* obase = out + ((long)b * 256 + co) * 3136 + p0 + rowb;
      #pragma unroll
      for (int r = 0; r < 4; ++r) obase[r] = acc[i][j][r];
    }
  }
}

// ---------------------------------------------------------------------------
extern "C" void kernel_launch(void* const* d_in, const int* in_sizes, int n_in,
                              void* d_out, int out_size, void* d_ws, size_t ws_size,
                              hipStream_t stream) {
  const float* x    = (const float*)d_in[0];
  const float* w11  = (const float*)d_in[1];
  const float* w13  = (const float*)d_in[2];
  const float* w15  = (const float*)d_in[3];
  const float* w17  = (const float*)d_in[4];
  const float* w21  = (const float*)d_in[5];
  const float* w23  = (const float*)d_in[6];
  const float* w25  = (const float*)d_in[7];
  const float* w27  = (const float*)d_in[8];
  const float* w2d1 = (const float*)d_in[9];
  const float* w2d2 = (const float*)d_in[10];
  float* out = (float*)d_out;

  unsigned short* ypad = (unsigned short*)d_ws;
  size_t ypad_elems = (size_t)64 * HP * WP * 256;       // 110 MB bf16
  unsigned short* wb1 = ypad + ypad_elems;
  unsigned short* wb2 = wb1 + 9 * 64 * 64;

  // wtab lives in the first 8KB of d_out: consumed by temporal_stage, then
  // fully overwritten by conv_gemm (which writes every output element).
  float* wtab = out;

  hipLaunchKernelGGL(wtab_prep, dim3(1), dim3(256), 0, stream,
                     w11, w13, w15, w17, w21, w23, w25, w27, wtab);
  hipLaunchKernelGGL(zero_ring, dim3(1824), dim3(256), 0, stream, (uint4*)ypad);
  hipLaunchKernelGGL(wprep, dim3(32),  dim3(256), 0, stream, w2d1, wb1, 64);
  hipLaunchKernelGGL(wprep, dim3(256), dim3(256), 0, stream, w2d2, wb2, 192);
  hipLaunchKernelGGL(temporal_stage, dim3(64 * 56), dim3(256), 0, stream, x, wtab, ypad);
  hipLaunchKernelGGL(conv_gemm, dim3(3136, 1), dim3(256), 0, stream, ypad, wb1, out, 64, 0, 0);
  hipLaunchKernelGGL(conv_gemm, dim3(3136, 3), dim3(256), 0, stream, ypad, wb2, out, 192, 64, 64);
}